// Round 1
// baseline (77.038 us; speedup 1.0000x reference)
//
#include <hip/hip_runtime.h>
#include <hip/hip_bf16.h>

// Problem: out[b,c] = sum_k w[b,k] * BivariateNormalPDF(X[b,c]; params[b,k])
// B=512, K=64, C=2048.
//
// Per-(b,k) preprocessing (threads 0..63 of each block, into LDS):
//   omr2 = 1 - r^2
//   a2   = 0.5*log2(e)/omr2          (positive)
//   sc   = sqrt(a2)
//   is1  = sc/s1, is2 = sc/s2        (scaled inverse sigmas)
//   mm1  = m1*is1, mm2 = m2*is2
//   wn   = w / (2*pi*s1*s2*sqrt(omr2))
// Then with dx = x1*is1 - mm1, dy = x2*is2 - mm2:
//   pdf*w = wn * exp2( 2r*dx*dy - (dx*dx + dy*dy) )
// Inner loop per eval: 7 FMA-class VALU + 1 native v_exp_f32.

constexpr int B = 512;
constexpr int K = 64;
constexpr int C = 2048;
constexpr int BLOCK = 256;

__global__ __launch_bounds__(BLOCK) void mixture_kernel(
    const float* __restrict__ mo,   // (B, K, 6)
    const float* __restrict__ X,    // (B, C, 2)
    float* __restrict__ out)        // (B, C)
{
    __shared__ float4 P[K][2];

    const int b = blockIdx.x;
    const int t = threadIdx.x;

    if (t < K) {
        const float* p = mo + ((size_t)(b * K + t)) * 6;
        const float w  = p[0];
        const float m1 = p[1];
        const float m2 = p[2];
        const float s1 = p[3];
        const float s2 = p[4];
        const float r  = p[5];

        const float omr2 = fmaf(-r, r, 1.0f);
        const float inv  = 1.0f / omr2;
        const float a2   = 0.7213475204444817f * inv;   // 0.5 * log2(e) / omr2
        const float sc   = sqrtf(a2);
        const float is1  = sc / s1;
        const float is2  = sc / s2;
        const float wn   = w * 0.15915494309189535f / (s1 * s2 * sqrtf(omr2));

        P[t][0] = make_float4(is1, is2, m1 * is1, m2 * is2);
        P[t][1] = make_float4(2.0f * r, wn, 0.0f, 0.0f);
    }
    __syncthreads();

    // Each thread handles 8 c-points: 4 coalesced float4 loads (2 points each).
    const float4* Xb = (const float4*)(X + (size_t)b * C * 2);
    float4 xv[4];
#pragma unroll
    for (int j = 0; j < 4; ++j) xv[j] = Xb[t + j * BLOCK];

    float acc[8];
#pragma unroll
    for (int i = 0; i < 8; ++i) acc[i] = 0.0f;

    for (int k = 0; k < K; ++k) {
        const float4 p0 = P[k][0];   // is1, is2, mm1, mm2  (LDS broadcast)
        const float4 p1 = P[k][1];   // 2r,  wn,  -,  -
#pragma unroll
        for (int j = 0; j < 4; ++j) {
            const float dx0 = fmaf(xv[j].x, p0.x, -p0.z);
            const float dy0 = fmaf(xv[j].y, p0.y, -p0.w);
            const float dx1 = fmaf(xv[j].z, p0.x, -p0.z);
            const float dy1 = fmaf(xv[j].w, p0.y, -p0.w);
            const float q0  = fmaf(dy0, dy0, dx0 * dx0);
            const float q1  = fmaf(dy1, dy1, dx1 * dx1);
            const float e0  = fmaf(p1.x, dx0 * dy0, -q0);
            const float e1  = fmaf(p1.x, dx1 * dy1, -q1);
            acc[2 * j]     = fmaf(p1.y, __builtin_amdgcn_exp2f(e0), acc[2 * j]);
            acc[2 * j + 1] = fmaf(p1.y, __builtin_amdgcn_exp2f(e1), acc[2 * j + 1]);
        }
    }

    float2* ob = (float2*)(out + (size_t)b * C);
#pragma unroll
    for (int j = 0; j < 4; ++j)
        ob[t + j * BLOCK] = make_float2(acc[2 * j], acc[2 * j + 1]);
}

extern "C" void kernel_launch(void* const* d_in, const int* in_sizes, int n_in,
                              void* d_out, int out_size, void* d_ws, size_t ws_size,
                              hipStream_t stream) {
    const float* mo = (const float*)d_in[0];   // (B,K,6) = 512*64*6
    const float* X  = (const float*)d_in[1];   // (B,C,2) = 512*2048*2
    float* out      = (float*)d_out;           // (B,C)

    mixture_kernel<<<dim3(B), dim3(BLOCK), 0, stream>>>(mo, X, out);
}

// Round 2
// 72.355 us; speedup vs baseline: 1.0647x; 1.0647x over previous
//
#include <hip/hip_runtime.h>
#include <hip/hip_bf16.h>

// out[b,c] = sum_k w[b,k] * BivariateNormalPDF(X[b,c]; params[b,k])
// B=512, K=64, C=2048.
//
// Per-(b,k) coefficients (threads 0..63 -> LDS, broadcast reads in k-loop):
//   is1 = sqrt(0.5*log2e/(1-r^2))/s1, is2 likewise, mm = m*is, 2r, wn.
// Inner eval: e = 2r*dx*dy - (dx^2+dy^2); out += wn * exp2(e).
// Points processed in packed fp32 pairs (v_pk_fma_f32/v_pk_mul_f32):
// 3.5 FMA-class instr + 1 v_exp_f32 per eval.

typedef float v2f __attribute__((ext_vector_type(2)));

constexpr int B = 512;
constexpr int K = 64;
constexpr int C = 2048;
constexpr int BLOCK = 256;
constexpr int HALVES = 2;         // split each batch's C range across 2 blocks
constexpr int CH = C / HALVES;    // 1024 c-points per block

__global__ __launch_bounds__(BLOCK, 4) void mixture_kernel(
    const float* __restrict__ mo,   // (B, K, 6)
    const float* __restrict__ X,    // (B, C, 2)
    float* __restrict__ out)        // (B, C)
{
    __shared__ float4 P[K][2];

    const int bid = blockIdx.x;
    const int b   = bid >> 1;
    const int h   = bid & 1;
    const int t   = threadIdx.x;

    if (t < K) {
        const float* p = mo + ((size_t)(b * K + t)) * 6;
        const float w  = p[0];
        const float m1 = p[1];
        const float m2 = p[2];
        const float s1 = p[3];
        const float s2 = p[4];
        const float r  = p[5];

        const float omr2 = fmaf(-r, r, 1.0f);
        const float inv  = 1.0f / omr2;
        const float a2   = 0.7213475204444817f * inv;   // 0.5*log2(e)/omr2
        const float sc   = sqrtf(a2);
        const float is1  = sc / s1;
        const float is2  = sc / s2;
        const float wn   = w * 0.15915494309189535f / (s1 * s2 * sqrtf(omr2));

        P[t][0] = make_float4(is1, is2, m1 * is1, m2 * is2);
        P[t][1] = make_float4(2.0f * r, wn, 0.0f, 0.0f);
    }
    __syncthreads();

    // 4 c-points per thread: 2 coalesced float4 loads (2 points each),
    // repacked into (x,x)/(y,y) pairs for packed fp32 math.
    const float4* Xb = (const float4*)(X + (size_t)b * C * 2 + (size_t)h * CH * 2);
    const float4 xv0 = Xb[t];
    const float4 xv1 = Xb[t + BLOCK];

    v2f xs[2] = { {xv0.x, xv0.z}, {xv1.x, xv1.z} };
    v2f ys[2] = { {xv0.y, xv0.w}, {xv1.y, xv1.w} };
    v2f acc[2] = { {0.0f, 0.0f}, {0.0f, 0.0f} };

#pragma unroll 4
    for (int k = 0; k < K; ++k) {
        const float4 p0 = P[k][0];   // is1, is2, mm1, mm2 (LDS broadcast)
        const float4 p1 = P[k][1];   // 2r, wn, -, -
        const v2f vis1 = { p0.x, p0.x };
        const v2f vis2 = { p0.y, p0.y };
        const v2f vnm1 = { -p0.z, -p0.z };
        const v2f vnm2 = { -p0.w, -p0.w };
        const v2f v2r  = { p1.x, p1.x };
        const v2f vwn  = { p1.y, p1.y };
#pragma unroll
        for (int j = 0; j < 2; ++j) {
            const v2f dx = __builtin_elementwise_fma(xs[j], vis1, vnm1);
            const v2f dy = __builtin_elementwise_fma(ys[j], vis2, vnm2);
            const v2f pq = dx * dy;
            v2f u        = dx * dx;
            u            = __builtin_elementwise_fma(dy, dy, u);
            const v2f e  = __builtin_elementwise_fma(v2r, pq, -u);
            v2f ex;
            ex.x = __builtin_amdgcn_exp2f(e.x);
            ex.y = __builtin_amdgcn_exp2f(e.y);
            acc[j] = __builtin_elementwise_fma(vwn, ex, acc[j]);
        }
    }

    float2* ob = (float2*)(out + (size_t)b * C + (size_t)h * CH);
    ob[t]         = make_float2(acc[0].x, acc[0].y);
    ob[t + BLOCK] = make_float2(acc[1].x, acc[1].y);
}

extern "C" void kernel_launch(void* const* d_in, const int* in_sizes, int n_in,
                              void* d_out, int out_size, void* d_ws, size_t ws_size,
                              hipStream_t stream) {
    const float* mo = (const float*)d_in[0];   // (B,K,6)
    const float* X  = (const float*)d_in[1];   // (B,C,2)
    float* out      = (float*)d_out;           // (B,C)

    mixture_kernel<<<dim3(B * HALVES), dim3(BLOCK), 0, stream>>>(mo, X, out);
}